// Round 18
// baseline (952.487 us; speedup 1.0000x reference)
//
#include <hip/hip_runtime.h>
#include <stdint.h>

typedef unsigned short u16;
typedef __bf16 bf16x8 __attribute__((ext_vector_type(8)));
typedef float f32x4 __attribute__((ext_vector_type(4)));
typedef unsigned uint32x4 __attribute__((ext_vector_type(4)));

#define DEVI __device__ __forceinline__

static constexpr int DIM = 768;
static constexpr int SEQL = 3136;   // 56*56
static constexpr int MROWS = 25088; // 8*3136
static constexpr int HEADS = 12;
static constexpr int HD = 64;
static constexpr int NW = 196;      // tokens per window
static constexpr float QSCALE = 0.125f; // 64^-0.5
// attn LDS: sP 4x[16][232]u16 29696 + sT 4x[16][65]f32 16640 -> 46336 (3 blocks/CU)
static constexpr int ATTN_SMEM = 46336;
static constexpr int GEMM_SMEM = 49152; // 3 A-buffers x 16KB; epilogue 4x[32][66]f32 fits

DEVI float b2f(u16 u) { union { unsigned i; float f; } v; v.i = ((unsigned)u) << 16; return v.f; }
DEVI u16 f2b(float f) { union { float f; unsigned u; } v; v.f = f; return (u16)((v.u + 0x7FFFu + ((v.u >> 16) & 1u)) >> 16); }
DEVI unsigned pack2(float a, float b) { return (unsigned)f2b(a) | ((unsigned)f2b(b) << 16); }
DEVI bf16x8 u4bf(uint4 u) { union { uint4 a; bf16x8 b; } c; c.a = u; return c.b; }

// cheap exact-enough GELU: x*sigmoid(1.5957691x + 0.0713548x^3), max |err| vs erf-GELU ~4e-4
DEVI float gelu_f(float x) {
  float x2 = x * x;
  float y = x * (1.5957691216f + 0.0713548162726f * x2);
  float e = __expf(-y);
  return x * __builtin_amdgcn_rcpf(1.f + e);
}

DEVI void gl_lds16(const void* g, void* l) {
  __builtin_amdgcn_global_load_lds((const __attribute__((address_space(1))) void*)g,
                                   (__attribute__((address_space(3))) void*)l, 16, 0, 0);
}

// 8B-aligned global bf16x8 load (two dwordx2)
DEVI bf16x8 ldg_b8(const u16* p) {
  union { uint4 u; bf16x8 v; } r;
  const uint2* p2 = (const uint2*)p;
  uint2 lo = p2[0], hi = p2[1];
  r.u.x = lo.x; r.u.y = lo.y; r.u.z = hi.x; r.u.w = hi.y;
  return r.v;
}

// ------- pack W[K][N] f32 -> MFMA-native fragment order bf16 (see R10 notes) -------
DEVI void pack_body(const float* __restrict__ in, u16* __restrict__ out,
                    int K, int N, int xb, int bn, int tid) {
  int f8 = xb * 256 + tid;
  int l = f8 & 63;
  int rest = f8 >> 6;
  int s = rest & 1, nf = (rest >> 1) & 3, wn2 = (rest >> 3) & 1, kt = rest >> 4;
  int n = bn * 128 + wn2 * 64 + nf * 16 + (l & 15);
  int kb = kt * 64 + s * 32 + (l >> 4) * 8;
  size_t obase = (((size_t)bn * (K >> 6) + kt) * 2 + wn2) * 4096 + (nf * 2 + s) * 512 + (size_t)l * 8;
  #pragma unroll
  for (int e = 0; e < 8; ++e)
    out[obase + e] = f2b(in[(size_t)(kb + e) * N + n]);
}

// fused prep: all 4 weight packs + rel-pos tables, one launch
__global__ __launch_bounds__(256)
void prep_all(const float* __restrict__ qkvw, const float* __restrict__ pjw,
              const float* __restrict__ f1w, const float* __restrict__ f2w,
              const float* __restrict__ rph, const float* __restrict__ rpw,
              u16* __restrict__ qkvwT, u16* __restrict__ projwT,
              u16* __restrict__ fc1wT, u16* __restrict__ fc2wT,
              u16* __restrict__ rpb) {
  const int bid = blockIdx.x, tid = threadIdx.x;
  if (bid < 864) {                       // qkv: (48 x 18)
    pack_body(qkvw, qkvwT, 768, 2304, bid % 48, bid / 48, tid);
  } else if (bid < 1152) {               // proj: (48 x 6)
    int r = bid - 864;  pack_body(pjw, projwT, 768, 768, r % 48, r / 48, tid);
  } else if (bid < 2304) {               // fc1: (48 x 24)
    int r = bid - 1152; pack_body(f1w, fc1wT, 768, 3072, r % 48, r / 48, tid);
  } else if (bid < 3456) {               // fc2: (192 x 6)
    int r = bid - 2304; pack_body(f2w, fc2wT, 3072, 768, r % 192, r / 192, tid);
  } else {                               // rel-pos tables: 16 blocks
    int i = (bid - 3456) * 256 + tid;    // 0..4095
    int tbl = i >> 11, r = (i >> 6) & 31, c = i & 63;
    float v = (r < 27) ? (tbl ? rpw : rph)[r * 64 + c] : 0.f;
    rpb[i] = f2b(v);
  }
}

// ---------------- layernorm v2: one wave per row (4 rows/block), 64-lane shuffle reduce ----
template<bool REMAP>
__global__ __launch_bounds__(256) void ln_kernel(const float* __restrict__ xin,
                                                 const float* __restrict__ g,
                                                 const float* __restrict__ bb,
                                                 u16* __restrict__ outw) {
  const int l = threadIdx.x & 63, w = threadIdx.x >> 6;
  const int r = blockIdx.x * 4 + w;
  const float* xr = xin + (size_t)r * DIM;
  f32x4 v[3], gv[3], bv[3];
  #pragma unroll
  for (int j = 0; j < 3; ++j) {
    v[j]  = *(const f32x4*)(xr + j * 256 + l * 4);
    gv[j] = *(const f32x4*)(g  + j * 256 + l * 4);
    bv[j] = *(const f32x4*)(bb + j * 256 + l * 4);
  }
  float s1 = 0.f, s2 = 0.f;
  #pragma unroll
  for (int j = 0; j < 3; ++j)
    #pragma unroll
    for (int e = 0; e < 4; ++e) { s1 += v[j][e]; s2 += v[j][e] * v[j][e]; }
  #pragma unroll
  for (int o = 1; o < 64; o <<= 1) { s1 += __shfl_xor(s1, o); s2 += __shfl_xor(s2, o); }
  float mean = s1 * (1.f / 768.f);
  float var = s2 * (1.f / 768.f) - mean * mean;
  float rstd = rsqrtf(var + 1e-5f);
  size_t orow;
  if constexpr (REMAP) {
    int b = r / SEQL, s = r % SEQL;
    int h = s / 56, ww = s % 56;
    orow = (size_t)(b * 16 + (h / 14) * 4 + (ww / 14)) * NW + (h % 14) * 14 + (ww % 14);
  } else {
    orow = (size_t)r;
  }
  u16* orp = outw + orow * DIM;
  #pragma unroll
  for (int j = 0; j < 3; ++j) {
    uint2 o2;
    o2.x = pack2((v[j][0] - mean) * rstd * gv[j][0] + bv[j][0],
                 (v[j][1] - mean) * rstd * gv[j][1] + bv[j][1]);
    o2.y = pack2((v[j][2] - mean) * rstd * gv[j][2] + bv[j][2],
                 (v[j][3] - mean) * rstd * gv[j][3] + bv[j][3]);
    *(uint2*)(orp + j * 256 + l * 4) = o2;
  }
}

// ------- GEMM v9 (R15/R17 best): 128x128, 4 waves, A in 3 rotating LDS buffers, B packed
//         from global with late-B register pipeline, 3 blocks/CU, supertile swizzle. ----
struct Epi {
  const float* bias;
  const float* x;   // proj: residual input (f32)
  float* outf;      // proj/fc2: f32 out (d_out)
  u16* q; u16* k; u16* v; // qkv outputs (v transposed: [wh][64][196])
  u16* o16;         // fc1 out
};

#define MFMA_BF16 __builtin_amdgcn_mfma_f32_16x16x32_bf16

template<int K, int N, int EPI>
__global__ __launch_bounds__(256, 3)
void gemm6_ep(const u16* __restrict__ A, const u16* __restrict__ Bp, Epi ep) {
  extern __shared__ __align__(16) char gsm[];   // 3 x 16KB A-buffers; epilogue reuse

  constexpr int NBN = N / 128;           // 18 / 6 / 24 / 6 -> divisible by 6
  constexpr int NSTC = NBN / 6;
  constexpr int NKT = K / 64;

  const int tid = threadIdx.x;
  const int l = tid & 63, w = tid >> 6;
  const int lr = l & 15, lg = l >> 4;

  // XCD-contiguous swizzle + 7x6 supertile decode (panel set per supertile fits L2)
  const int nwg = gridDim.x;
  const int cpx = nwg >> 3;
  const int wg = (blockIdx.x & 7) * cpx + (blockIdx.x >> 3);
  const int st = wg / 42, r42 = wg - st * 42;
  const int bm = (st / NSTC) * 7 + r42 / 6;
  const int bn = (st - (st / NSTC) * NSTC) * 6 + r42 - (r42 / 6) * 6;
  const int wm = (w >> 1) * 64, wn = (w & 1) * 64;   // wave tile 64x64

  const u16* Ab = A + (size_t)bm * 128 * K;
  const u16* Bw = Bp + (((size_t)bn * NKT) * 2 + (w & 1)) * 4096 + (size_t)l * 8;

  int srcoff[4];
  #pragma unroll
  for (int p = 0; p < 4; ++p) {
    int si = p * 256 + tid;
    int row = si >> 3;
    srcoff[p] = row * K + (((si & 7) ^ (row & 7)) << 3);
  }
  #define STG(kt, buf) do {                                                     \
    char* _d = gsm + (buf) * 16384;                                             \
    _Pragma("unroll")                                                           \
    for (int _p = 0; _p < 4; ++_p)                                              \
      gl_lds16(Ab + srcoff[_p] + (size_t)(kt) * 64, _d + _p * 4096 + tid * 16); \
  } while (0)

  #define LDB(kt) do {                                                          \
    const u16* _bt = Bw + (size_t)(kt) * 8192;                                  \
    _Pragma("unroll")                                                           \
    for (int _nf = 0; _nf < 4; ++_nf)                                           \
      _Pragma("unroll")                                                         \
      for (int _s = 0; _s < 2; ++_s)                                            \
        braw[_nf][_s] = *(const uint4*)(_bt + (_nf * 2 + _s) * 512);            \
  } while (0)

  const int p0 = lg ^ (lr & 7);   // phys slot, k-slice 0
  const int p1 = p0 ^ 4;          // phys slot, k-slice 1

  f32x4 zero4 = {0.f, 0.f, 0.f, 0.f};
  f32x4 acc[4][4];
  #pragma unroll
  for (int i = 0; i < 4; ++i)
    #pragma unroll
    for (int j = 0; j < 4; ++j) acc[i][j] = zero4;

  uint4 braw[4][2];

  // prologue: A(0),A(1) staged; B(0) issued early
  STG(0, 0);
  STG(1, 1);
  LDB(0);

  for (int t = 0; t < NKT; ++t) {
    if (t == 0) asm volatile("s_waitcnt vmcnt(12)" ::: "memory");
    __builtin_amdgcn_s_barrier();

    if (t + 2 < NKT) STG(t + 2, (t + 2) % 3);   // buffer free: last read at t-1

    const u16* cA = (const u16*)(gsm + (t % 3) * 16384);
    bf16x8 af[4][2];
    #pragma unroll
    for (int mf = 0; mf < 4; ++mf) {
      af[mf][0] = *(const bf16x8*)(cA + (wm + mf * 16 + lr) * 64 + p0 * 8);
      af[mf][1] = *(const bf16x8*)(cA + (wm + mf * 16 + lr) * 64 + p1 * 8);
    }
    __builtin_amdgcn_s_setprio(1);
    #pragma unroll
    for (int mf = 0; mf < 4; ++mf)
      #pragma unroll
      for (int nf = 0; nf < 4; ++nf) {
        acc[mf][nf] = MFMA_BF16(af[mf][0], u4bf(braw[nf][0]), acc[mf][nf], 0, 0, 0);
        acc[mf][nf] = MFMA_BF16(af[mf][1], u4bf(braw[nf][1]), acc[mf][nf], 0, 0, 0);
      }
    __builtin_amdgcn_s_setprio(0);

    if (t + 1 < NKT) LDB(t + 1);   // late-B: WAR keeps this after the MFMAs
  }
  #undef LDB
  #undef STG

  // ---- epilogue: 2-pass LDS transpose ([32][66] f32 per wave) + wide nt stores ----
  __syncthreads();
  float* tp = (float*)(gsm + w * 8448);
  const int ccl = (l & 3) * 16;
  const int cbase = bn * 128 + wn + ccl;
  f32x4 bs[4];
  #pragma unroll
  for (int jj = 0; jj < 4; ++jj) bs[jj] = *(const f32x4*)(ep.bias + cbase + jj * 4);

  #pragma unroll
  for (int q = 0; q < 2; ++q) {
    if (q == 1) { asm volatile("s_waitcnt lgkmcnt(0)" ::: "memory"); __builtin_amdgcn_sched_barrier(0); }
    #pragma unroll
    for (int mf2 = 0; mf2 < 2; ++mf2)
      #pragma unroll
      for (int nf = 0; nf < 4; ++nf)
        #pragma unroll
        for (int e = 0; e < 4; ++e)
          tp[(mf2 * 16 + lg * 4 + e) * 66 + nf * 16 + lr] = acc[q * 2 + mf2][nf][e];
    asm volatile("s_waitcnt lgkmcnt(0)" ::: "memory");
    __builtin_amdgcn_sched_barrier(0);

    #pragma unroll
    for (int pp = 0; pp < 2; ++pp) {
      const int rowl = pp * 16 + (l >> 2);
      const int r = bm * 128 + wm + q * 32 + rowl;
      const int c = cbase;
      f32x4 vv[4];
      #pragma unroll
      for (int jj = 0; jj < 4; ++jj) {
        #pragma unroll
        for (int j2 = 0; j2 < 4; ++j2)
          vv[jj][j2] = tp[rowl * 66 + ccl + jj * 4 + j2];
        vv[jj] += bs[jj];
      }

      if constexpr (EPI == 0) { // qkv: q/k wide nt; v scalar nt scatter (transposed layout)
        const int which = c / DIM;
        const int hdc = c - which * DIM;
        const int head = hdc >> 6, d0 = hdc & 63;
        const int win = r / NW, pos = r - win * NW;
        const size_t wh = (size_t)win * HEADS + head;
        if (which == 0) {
          uint32x4 o0, o1;
          o0[0] = pack2(vv[0][0] * QSCALE, vv[0][1] * QSCALE);
          o0[1] = pack2(vv[0][2] * QSCALE, vv[0][3] * QSCALE);
          o0[2] = pack2(vv[1][0] * QSCALE, vv[1][1] * QSCALE);
          o0[3] = pack2(vv[1][2] * QSCALE, vv[1][3] * QSCALE);
          o1[0] = pack2(vv[2][0] * QSCALE, vv[2][1] * QSCALE);
          o1[1] = pack2(vv[2][2] * QSCALE, vv[2][3] * QSCALE);
          o1[2] = pack2(vv[3][0] * QSCALE, vv[3][1] * QSCALE);
          o1[3] = pack2(vv[3][2] * QSCALE, vv[3][3] * QSCALE);
          u16* dst = ep.q + (wh * NW + pos) * HD + d0;
          __builtin_nontemporal_store(o0, (uint32x4*)dst);
          __builtin_nontemporal_store(o1, (uint32x4*)(dst + 8));
        } else if (which == 1) {
          uint32x4 o0, o1;
          o0[0] = pack2(vv[0][0], vv[0][1]); o0[1] = pack2(vv[0][2], vv[0][3]);
          o0[2] = pack2(vv[1][0], vv[1][1]); o0[3] = pack2(vv[1][2], vv[1][3]);
          o1[0] = pack2(vv[2][0], vv[2][1]); o1[1] = pack2(vv[2][2], vv[2][3]);
          o1[2] = pack2(vv[3][0], vv[3][1]); o1[3] = pack2(vv[3][2], vv[3][3]);
          u16* dst = ep.k + (wh * NW + pos) * HD + d0;
          __builtin_nontemporal_store(o0, (uint32x4*)dst);
          __builtin_nontemporal_store(o1, (uint32x4*)(dst + 8));
        } else {
          // scalar scatter: for fixed d, 16 lanes write consecutive pos -> HW-coalesced
          #pragma unroll
          for (int jj = 0; jj < 4; ++jj)
            #pragma unroll
            for (int j2 = 0; j2 < 4; ++j2)
              __builtin_nontemporal_store(f2b(vv[jj][j2]),
                  ep.v + (wh * HD + d0 + jj * 4 + j2) * NW + pos);
        }
      } else if constexpr (EPI == 1) { // proj: window-reverse + residual -> f32 d_out
        const int win = r / NW, pos = r - win * NW;
        const int b = win >> 4, wi = win & 15;
        const int hh = (wi >> 2) * 14 + pos / 14;
        const int ww2 = (wi & 3) * 14 + pos % 14;
        const size_t orow = (size_t)b * SEQL + hh * 56 + ww2;
        const f32x4* px = (const f32x4*)(ep.x + orow * DIM + c);
        f32x4* po = (f32x4*)(ep.outf + orow * DIM + c);
        #pragma unroll
        for (int jj = 0; jj < 4; ++jj) {
          f32x4 t2 = px[jj] + vv[jj];
          __builtin_nontemporal_store(t2, po + jj);
        }
      } else if constexpr (EPI == 2) { // fc1: cheap GELU -> bf16 wide nt
        float gg[16];
        #pragma unroll
        for (int jj = 0; jj < 4; ++jj)
          #pragma unroll
          for (int j2 = 0; j2 < 4; ++j2)
            gg[jj * 4 + j2] = gelu_f(vv[jj][j2]);
        uint32x4 o0, o1;
        o0[0] = pack2(gg[0], gg[1]);   o0[1] = pack2(gg[2], gg[3]);
        o0[2] = pack2(gg[4], gg[5]);   o0[3] = pack2(gg[6], gg[7]);
        o1[0] = pack2(gg[8], gg[9]);   o1[1] = pack2(gg[10], gg[11]);
        o1[2] = pack2(gg[12], gg[13]); o1[3] = pack2(gg[14], gg[15]);
        u16* dst = ep.o16 + (size_t)r * N + c;
        __builtin_nontemporal_store(o0, (uint32x4*)dst);
        __builtin_nontemporal_store(o1, (uint32x4*)(dst + 8));
      } else { // fc2: residual with d_out (x1): cached read, nt write
        f32x4* po = (f32x4*)(ep.outf + (size_t)r * N + c);
        #pragma unroll
        for (int jj = 0; jj < 4; ++jj) {
          f32x4 t2 = po[jj] + vv[jj];
          __builtin_nontemporal_store(t2, po + jj);
        }
      }
    }
  }
}

// ------ fused window attention v5: no sK (K from global/L2), barrier-free, 3 blocks/CU ----
__global__ __launch_bounds__(256, 3)
void attn_kernel(const u16* __restrict__ qbuf, const u16* __restrict__ kbuf,
                 const u16* __restrict__ vt, const u16* __restrict__ rpb,
                 u16* __restrict__ abuf) {
  extern __shared__ __align__(16) char smem[];
  u16* sP = (u16*)smem;                  // 4 x [16][232]
  float* sT = (float*)(smem + 29696);    // 4 x [16][65] (stride 65 -> row r at bank r)

  const int tid = threadIdx.x;
  const int l = tid & 63, w = tid >> 6;
  const int lr = l & 15, lg = l >> 4;
  const int wh = blockIdx.x;             // win*12 + head
  const int win = wh / HEADS, head = wh - win * HEADS;

  const u16* Qg = qbuf + (size_t)wh * (NW * HD);
  const u16* Kg = kbuf + (size_t)wh * (NW * HD);
  const u16* Vg = vt + (size_t)wh * (HD * NW);   // [64][196]

  f32x4 zero4 = {0.f, 0.f, 0.f, 0.f};
  u16* myP = sP + w * (16 * 232);
  float* myT = sT + w * (16 * 65);

  for (int c = 0; c < 4; ++c) {
    const int chunk = w + 4 * c;
    if (chunk > 12) break;

    int qrow = chunk * 16 + lr; if (qrow > 195) qrow = 195;
    bf16x8 aq0 = *(const bf16x8*)(Qg + (size_t)qrow * HD + lg * 8);
    bf16x8 aq1 = *(const bf16x8*)(Qg + (size_t)qrow * HD + 32 + lg * 8);

    f32x4 th[2], tw[2];
    #pragma unroll
    for (int nf2 = 0; nf2 < 2; ++nf2) {
      const u16* bh = rpb + (nf2 * 16 + lr) * 64;
      const u16* bw = rpb + 2048 + (nf2 * 16 + lr) * 64;
      f32x4 a = zero4, b = zero4;
      a = MFMA_BF16(aq0, *(const bf16x8*)(bh + lg * 8), a, 0, 0, 0);
      a = MFMA_BF16(aq1, *(const bf16x8*)(bh + 32 + lg * 8), a, 0, 0, 0);
      b = MFMA_BF16(aq0, *(const bf16x8*)(bw + lg * 8), b, 0, 0, 0);
      b = MFMA_BF16(aq1, *(const bf16x8*)(bw + 32 + lg * 8), b, 0, 0, 0);
      th[nf2] = a; tw[nf2] = b;
    }
    #pragma unroll
    for (int nf2 = 0; nf2 < 2; ++nf2)
      #pragma unroll
      for (int e = 0; e < 4; ++e) {
        myT[(lg * 4 + e) * 65 + nf2 * 16 + lr]      = th[nf2][e];
        myT[(lg * 4 + e) * 65 + 32 + nf2 * 16 + lr] = tw[nf2][e];
      }

    // ---- QK^T: K fragments straight from global (L2-hot; rows 196..207 finite garbage,
    //      masked below; last wh reads into vtb region -> in-bounds, finite) ----
    f32x4 accs[13];
    #pragma unroll
    for (int nf = 0; nf < 13; ++nf) {
      int krow = nf * 16 + lr;
      bf16x8 b0 = *(const bf16x8*)(Kg + (size_t)krow * HD + lg * 8);
      bf16x8 b1 = *(const bf16x8*)(Kg + (size_t)krow * HD + 32 + lg * 8);
      f32x4 cc = zero4;
      cc = MFMA_BF16(aq0, b0, cc, 0, 0, 0);
      cc = MFMA_BF16(aq1, b1, cc, 0, 0, 0);
      accs[nf] = cc;
    }

    int ihv[4], iwv[4];
    #pragma unroll
    for (int e = 0; e < 4; ++e) {
      int gi = chunk * 16 + lg * 4 + e;
      ihv[e] = (gi * 9363) >> 17;
      iwv[e] = gi - ihv[e] * 14;
    }
    float mrow[4] = {-3e38f, -3e38f, -3e38f, -3e38f};
    #pragma unroll
    for (int nf = 0; nf < 13; ++nf) {
      int j = nf * 16 + lr;
      int jh = (j * 9363) >> 17;
      int jw = j - jh * 14;
      #pragma unroll
      for (int e = 0; e < 4; ++e) {
        int ic = lg * 4 + e;
        float s = accs[nf][e]
                + myT[ic * 65 + ((ihv[e] - jh + 13) & 63)]
                + myT[ic * 65 + 32 + (iwv[e] - jw + 13)];
        if (nf == 12 && lr >= 4) s = -1e30f;
        accs[nf][e] = s;
        mrow[e] = fmaxf(mrow[e], s);
      }
    }
    #pragma unroll
    for (int e = 0; e < 4; ++e) {
      float v = mrow[e];
      v = fmaxf(v, __shfl_xor(v, 1)); v = fmaxf(v, __shfl_xor(v, 2));
      v = fmaxf(v, __shfl_xor(v, 4)); v = fmaxf(v, __shfl_xor(v, 8));
      mrow[e] = v;
    }
    float ssum[4] = {0.f, 0.f, 0.f, 0.f};
    #pragma unroll
    for (int nf = 0; nf < 13; ++nf)
      #pragma unroll
      for (int e = 0; e < 4; ++e) {
        float p = __expf(accs[nf][e] - mrow[e]);
        accs[nf][e] = p;
        ssum[e] += p;
      }
    #pragma unroll
    for (int e = 0; e < 4; ++e) {
      float v = ssum[e];
      v += __shfl_xor(v, 1); v += __shfl_xor(v, 2);
      v += __shfl_xor(v, 4); v += __shfl_xor(v, 8);
      ssum[e] = 1.f / v;
    }
    #pragma unroll
    for (int nf = 0; nf < 13; ++nf)
      #pragma unroll
      for (int e = 0; e < 4; ++e)
        myP[(lg * 4 + e) * 232 + nf * 16 + lr] = f2b(accs[nf][e] * ssum[e]);
    #pragma unroll
    for (int e = 0; e < 4; ++e)
      myP[(lg * 4 + e) * 232 + 208 + lr] = 0;

    f32x4 acco[4];
    #pragma unroll
    for (int nf = 0; nf < 4; ++nf) acco[nf] = zero4;
    #pragma unroll
    for (int ks = 0; ks < 7; ++ks) {
      bf16x8 ap = *(const bf16x8*)(myP + lr * 232 + ks * 32 + lg * 8);
      #pragma unroll
      for (int nf = 0; nf < 4; ++nf) {
        bf16x8 bv = ldg_b8(Vg + (size_t)(nf * 16 + lr) * NW + ks * 32 + lg * 8);
        acco[nf] = MFMA_BF16(ap, bv, acco[nf], 0, 0, 0);
      }
    }
    u16* ob = abuf + (size_t)win * NW * DIM + head * HD;
    #pragma unroll
    for (int nf = 0; nf < 4; ++nf)
      #pragma unroll
      for (int e = 0; e < 4; ++e) {
        int row = chunk * 16 + lg * 4 + e;
        if (row < 196) ob[(size_t)row * DIM + nf * 16 + lr] = f2b(acco[nf][e]);
      }
  }
}

// ---------------- host launch ---------------
extern "C" void kernel_launch(void* const* d_in, const int* in_sizes, int n_in,
                              void* d_out, int out_size, void* d_ws, size_t ws_size,
                              hipStream_t stream) {
  (void)in_sizes; (void)n_in; (void)out_size; (void)ws_size;
  const float* x    = (const float*)d_in[0];
  const float* ln1s = (const float*)d_in[1];
  const float* ln1b = (const float*)d_in[2];
  const float* qkvw = (const float*)d_in[3];
  const float* qkvb = (const float*)d_in[4];
  const float* rph  = (const float*)d_in[5];
  const float* rpw  = (const float*)d_in[6];
  const float* pjw  = (const float*)d_in[7];
  const float* pjb  = (const float*)d_in[8];
  const float* ln2s = (const float*)d_in[9];
  const float* ln2b = (const float*)d_in[10];
  const float* f1w  = (const float*)d_in[11];
  const float* f1b  = (const float*)d_in[12];
  const float* f2w  = (const float*)d_in[13];
  const float* f2b_ = (const float*)d_in[14];
  float* out = (float*)d_out;

  char* ws = (char*)d_ws;
  u16* qkvwT = (u16*)ws;              // packed [2304x768]
  u16* projwT = qkvwT + 1769472;      // packed [768x768]
  u16* fc1wT  = qkvwT + 2359296;      // packed [3072x768]
  u16* fc2wT  = qkvwT + 4718592;      // packed [768x3072]
  u16* xw   = (u16*)(ws + 14155776);  // [25088][768]
  u16* qbuf = (u16*)(ws + 52690944);  // [1536][196][64]
  u16* kbuf = qbuf + 19267584;
  u16* vtb  = kbuf + 19267584;        // [1536][64][196]
  u16* h2   = (u16*)(ws + 168296448); // [25088][768]
  u16* abuf = xw;                     // alias (xw dead after qkv gemm)
  u16* h1   = xw;                     // [25088][3072] spans xw+q+k+vT regions (all dead)
  u16* rpb  = h2;                     // [2][32][64] bf16 tables; h2 written only after attn

  (void)hipFuncSetAttribute((const void*)attn_kernel,
                            hipFuncAttributeMaxDynamicSharedMemorySize, ATTN_SMEM);
  (void)hipFuncSetAttribute((const void*)gemm6_ep<768, 2304, 0>,
                            hipFuncAttributeMaxDynamicSharedMemorySize, GEMM_SMEM);
  (void)hipFuncSetAttribute((const void*)gemm6_ep<768, 768, 1>,
                            hipFuncAttributeMaxDynamicSharedMemorySize, GEMM_SMEM);
  (void)hipFuncSetAttribute((const void*)gemm6_ep<768, 3072, 2>,
                            hipFuncAttributeMaxDynamicSharedMemorySize, GEMM_SMEM);
  (void)hipFuncSetAttribute((const void*)gemm6_ep<3072, 768, 3>,
                            hipFuncAttributeMaxDynamicSharedMemorySize, GEMM_SMEM);

  prep_all<<<3472, 256, 0, stream>>>(qkvw, pjw, f1w, f2w, rph, rpw,
                                     qkvwT, projwT, fc1wT, fc2wT, rpb);

  ln_kernel<true><<<MROWS / 4, 256, 0, stream>>>(x, ln1s, ln1b, xw);

  { Epi e{}; e.bias = qkvb; e.q = qbuf; e.k = kbuf; e.v = vtb;
    gemm6_ep<768, 2304, 0><<<196 * 18, 256, GEMM_SMEM, stream>>>(xw, qkvwT, e); }

  attn_kernel<<<1536, 256, ATTN_SMEM, stream>>>(qbuf, kbuf, vtb, rpb, abuf);

  { Epi e{}; e.bias = pjb; e.x = x; e.outf = out;
    gemm6_ep<768, 768, 1><<<196 * 6, 256, GEMM_SMEM, stream>>>(abuf, projwT, e); }

  ln_kernel<false><<<MROWS / 4, 256, 0, stream>>>(out, ln2s, ln2b, h2);

  { Epi e{}; e.bias = f1b; e.o16 = h1;
    gemm6_ep<768, 3072, 2><<<196 * 24, 256, GEMM_SMEM, stream>>>(h2, fc1wT, e); }

  { Epi e{}; e.bias = f2b_; e.outf = out;
    gemm6_ep<3072, 768, 3><<<196 * 6, 256, GEMM_SMEM, stream>>>(h1, fc2wT, e); }
}

// Round 19
// 711.203 us; speedup vs baseline: 1.3393x; 1.3393x over previous
//
#include <hip/hip_runtime.h>
#include <stdint.h>

typedef unsigned short u16;
typedef __bf16 bf16x8 __attribute__((ext_vector_type(8)));
typedef float f32x4 __attribute__((ext_vector_type(4)));
typedef unsigned uint32x4 __attribute__((ext_vector_type(4)));

#define DEVI __device__ __forceinline__

static constexpr int DIM = 768;
static constexpr int SEQL = 3136;   // 56*56
static constexpr int MROWS = 25088; // 8*3136
static constexpr int HEADS = 12;
static constexpr int HD = 64;
static constexpr int NW = 196;      // tokens per window
static constexpr float QSCALE = 0.125f; // 64^-0.5
// sK 26624 + sP 29696 + sT 4*16*65*4=16640 -> 72960 (2 blocks/CU)
static constexpr int ATTN_SMEM = 72960;
static constexpr int GEMM_SMEM = 49152; // 3 A-buffers x 16KB; epilogue 4x[32][66]f32 fits

DEVI float b2f(u16 u) { union { unsigned i; float f; } v; v.i = ((unsigned)u) << 16; return v.f; }
DEVI u16 f2b(float f) { union { float f; unsigned u; } v; v.f = f; return (u16)((v.u + 0x7FFFu + ((v.u >> 16) & 1u)) >> 16); }
DEVI unsigned pack2(float a, float b) { return (unsigned)f2b(a) | ((unsigned)f2b(b) << 16); }
DEVI bf16x8 u4bf(uint4 u) { union { uint4 a; bf16x8 b; } c; c.a = u; return c.b; }

// cheap exact-enough GELU: x*sigmoid(1.5957691x + 0.0713548x^3), max |err| vs erf-GELU ~4e-4
DEVI float gelu_f(float x) {
  float x2 = x * x;
  float y = x * (1.5957691216f + 0.0713548162726f * x2);
  float e = __expf(-y);
  return x * __builtin_amdgcn_rcpf(1.f + e);
}

DEVI void gl_lds16(const void* g, void* l) {
  __builtin_amdgcn_global_load_lds((const __attribute__((address_space(1))) void*)g,
                                   (__attribute__((address_space(3))) void*)l, 16, 0, 0);
}

// 8B-aligned global bf16x8 load (two dwordx2)
DEVI bf16x8 ldg_b8(const u16* p) {
  union { uint4 u; bf16x8 v; } r;
  const uint2* p2 = (const uint2*)p;
  uint2 lo = p2[0], hi = p2[1];
  r.u.x = lo.x; r.u.y = lo.y; r.u.z = hi.x; r.u.w = hi.y;
  return r.v;
}

// ------- pack W[K][N] f32 -> MFMA-native fragment order bf16 (see R10 notes) -------
DEVI void pack_body(const float* __restrict__ in, u16* __restrict__ out,
                    int K, int N, int xb, int bn, int tid) {
  int f8 = xb * 256 + tid;
  int l = f8 & 63;
  int rest = f8 >> 6;
  int s = rest & 1, nf = (rest >> 1) & 3, wn2 = (rest >> 3) & 1, kt = rest >> 4;
  int n = bn * 128 + wn2 * 64 + nf * 16 + (l & 15);
  int kb = kt * 64 + s * 32 + (l >> 4) * 8;
  size_t obase = (((size_t)bn * (K >> 6) + kt) * 2 + wn2) * 4096 + (nf * 2 + s) * 512 + (size_t)l * 8;
  #pragma unroll
  for (int e = 0; e < 8; ++e)
    out[obase + e] = f2b(in[(size_t)(kb + e) * N + n]);
}

// fused prep: all 4 weight packs + rel-pos tables, one launch
__global__ __launch_bounds__(256)
void prep_all(const float* __restrict__ qkvw, const float* __restrict__ pjw,
              const float* __restrict__ f1w, const float* __restrict__ f2w,
              const float* __restrict__ rph, const float* __restrict__ rpw,
              u16* __restrict__ qkvwT, u16* __restrict__ projwT,
              u16* __restrict__ fc1wT, u16* __restrict__ fc2wT,
              u16* __restrict__ rpb) {
  const int bid = blockIdx.x, tid = threadIdx.x;
  if (bid < 864) {                       // qkv: (48 x 18)
    pack_body(qkvw, qkvwT, 768, 2304, bid % 48, bid / 48, tid);
  } else if (bid < 1152) {               // proj: (48 x 6)
    int r = bid - 864;  pack_body(pjw, projwT, 768, 768, r % 48, r / 48, tid);
  } else if (bid < 2304) {               // fc1: (48 x 24)
    int r = bid - 1152; pack_body(f1w, fc1wT, 768, 3072, r % 48, r / 48, tid);
  } else if (bid < 3456) {               // fc2: (192 x 6)
    int r = bid - 2304; pack_body(f2w, fc2wT, 3072, 768, r % 192, r / 192, tid);
  } else {                               // rel-pos tables: 16 blocks
    int i = (bid - 3456) * 256 + tid;    // 0..4095
    int tbl = i >> 11, r = (i >> 6) & 31, c = i & 63;
    float v = (r < 27) ? (tbl ? rpw : rph)[r * 64 + c] : 0.f;
    rpb[i] = f2b(v);
  }
}

// ---------------- layernorm v2: one wave per row (4 rows/block), 64-lane shuffle reduce ----
template<bool REMAP>
__global__ __launch_bounds__(256) void ln_kernel(const float* __restrict__ xin,
                                                 const float* __restrict__ g,
                                                 const float* __restrict__ bb,
                                                 u16* __restrict__ outw) {
  const int l = threadIdx.x & 63, w = threadIdx.x >> 6;
  const int r = blockIdx.x * 4 + w;
  const float* xr = xin + (size_t)r * DIM;
  f32x4 v[3], gv[3], bv[3];
  #pragma unroll
  for (int j = 0; j < 3; ++j) {
    v[j]  = *(const f32x4*)(xr + j * 256 + l * 4);
    gv[j] = *(const f32x4*)(g  + j * 256 + l * 4);
    bv[j] = *(const f32x4*)(bb + j * 256 + l * 4);
  }
  float s1 = 0.f, s2 = 0.f;
  #pragma unroll
  for (int j = 0; j < 3; ++j)
    #pragma unroll
    for (int e = 0; e < 4; ++e) { s1 += v[j][e]; s2 += v[j][e] * v[j][e]; }
  #pragma unroll
  for (int o = 1; o < 64; o <<= 1) { s1 += __shfl_xor(s1, o); s2 += __shfl_xor(s2, o); }
  float mean = s1 * (1.f / 768.f);
  float var = s2 * (1.f / 768.f) - mean * mean;
  float rstd = rsqrtf(var + 1e-5f);
  size_t orow;
  if constexpr (REMAP) {
    int b = r / SEQL, s = r % SEQL;
    int h = s / 56, ww = s % 56;
    orow = (size_t)(b * 16 + (h / 14) * 4 + (ww / 14)) * NW + (h % 14) * 14 + (ww % 14);
  } else {
    orow = (size_t)r;
  }
  u16* orp = outw + orow * DIM;
  #pragma unroll
  for (int j = 0; j < 3; ++j) {
    uint2 o2;
    o2.x = pack2((v[j][0] - mean) * rstd * gv[j][0] + bv[j][0],
                 (v[j][1] - mean) * rstd * gv[j][1] + bv[j][1]);
    o2.y = pack2((v[j][2] - mean) * rstd * gv[j][2] + bv[j][2],
                 (v[j][3] - mean) * rstd * gv[j][3] + bv[j][3]);
    *(uint2*)(orp + j * 256 + l * 4) = o2;
  }
}

// ------- GEMM v9 (R15/R17 best): 128x128, 4 waves, A in 3 rotating LDS buffers, B packed
//         from global with late-B register pipeline, 3 blocks/CU, supertile swizzle. ----
struct Epi {
  const float* bias;
  const float* x;   // proj: residual input (f32)
  float* outf;      // proj/fc2: f32 out (d_out)
  u16* q; u16* k; u16* v; // qkv outputs (v transposed: [wh][64][196])
  u16* o16;         // fc1 out
};

#define MFMA_BF16 __builtin_amdgcn_mfma_f32_16x16x32_bf16

template<int K, int N, int EPI>
__global__ __launch_bounds__(256, 3)
void gemm6_ep(const u16* __restrict__ A, const u16* __restrict__ Bp, Epi ep) {
  extern __shared__ __align__(16) char gsm[];   // 3 x 16KB A-buffers; epilogue reuse

  constexpr int NBN = N / 128;           // 18 / 6 / 24 / 6 -> divisible by 6
  constexpr int NSTC = NBN / 6;
  constexpr int NKT = K / 64;

  const int tid = threadIdx.x;
  const int l = tid & 63, w = tid >> 6;
  const int lr = l & 15, lg = l >> 4;

  // XCD-contiguous swizzle + 7x6 supertile decode (panel set per supertile fits L2)
  const int nwg = gridDim.x;
  const int cpx = nwg >> 3;
  const int wg = (blockIdx.x & 7) * cpx + (blockIdx.x >> 3);
  const int st = wg / 42, r42 = wg - st * 42;
  const int bm = (st / NSTC) * 7 + r42 / 6;
  const int bn = (st - (st / NSTC) * NSTC) * 6 + r42 - (r42 / 6) * 6;
  const int wm = (w >> 1) * 64, wn = (w & 1) * 64;   // wave tile 64x64

  const u16* Ab = A + (size_t)bm * 128 * K;
  const u16* Bw = Bp + (((size_t)bn * NKT) * 2 + (w & 1)) * 4096 + (size_t)l * 8;

  int srcoff[4];
  #pragma unroll
  for (int p = 0; p < 4; ++p) {
    int si = p * 256 + tid;
    int row = si >> 3;
    srcoff[p] = row * K + (((si & 7) ^ (row & 7)) << 3);
  }
  #define STG(kt, buf) do {                                                     \
    char* _d = gsm + (buf) * 16384;                                             \
    _Pragma("unroll")                                                           \
    for (int _p = 0; _p < 4; ++_p)                                              \
      gl_lds16(Ab + srcoff[_p] + (size_t)(kt) * 64, _d + _p * 4096 + tid * 16); \
  } while (0)

  #define LDB(kt) do {                                                          \
    const u16* _bt = Bw + (size_t)(kt) * 8192;                                  \
    _Pragma("unroll")                                                           \
    for (int _nf = 0; _nf < 4; ++_nf)                                           \
      _Pragma("unroll")                                                         \
      for (int _s = 0; _s < 2; ++_s)                                            \
        braw[_nf][_s] = *(const uint4*)(_bt + (_nf * 2 + _s) * 512);            \
  } while (0)

  const int p0 = lg ^ (lr & 7);   // phys slot, k-slice 0
  const int p1 = p0 ^ 4;          // phys slot, k-slice 1

  f32x4 zero4 = {0.f, 0.f, 0.f, 0.f};
  f32x4 acc[4][4];
  #pragma unroll
  for (int i = 0; i < 4; ++i)
    #pragma unroll
    for (int j = 0; j < 4; ++j) acc[i][j] = zero4;

  uint4 braw[4][2];

  // prologue: A(0),A(1) staged; B(0) issued early
  STG(0, 0);
  STG(1, 1);
  LDB(0);

  for (int t = 0; t < NKT; ++t) {
    if (t == 0) asm volatile("s_waitcnt vmcnt(12)" ::: "memory");
    __builtin_amdgcn_s_barrier();

    if (t + 2 < NKT) STG(t + 2, (t + 2) % 3);   // buffer free: last read at t-1

    const u16* cA = (const u16*)(gsm + (t % 3) * 16384);
    bf16x8 af[4][2];
    #pragma unroll
    for (int mf = 0; mf < 4; ++mf) {
      af[mf][0] = *(const bf16x8*)(cA + (wm + mf * 16 + lr) * 64 + p0 * 8);
      af[mf][1] = *(const bf16x8*)(cA + (wm + mf * 16 + lr) * 64 + p1 * 8);
    }
    __builtin_amdgcn_s_setprio(1);
    #pragma unroll
    for (int mf = 0; mf < 4; ++mf)
      #pragma unroll
      for (int nf = 0; nf < 4; ++nf) {
        acc[mf][nf] = MFMA_BF16(af[mf][0], u4bf(braw[nf][0]), acc[mf][nf], 0, 0, 0);
        acc[mf][nf] = MFMA_BF16(af[mf][1], u4bf(braw[nf][1]), acc[mf][nf], 0, 0, 0);
      }
    __builtin_amdgcn_s_setprio(0);

    if (t + 1 < NKT) LDB(t + 1);   // late-B: WAR keeps this after the MFMAs
  }
  #undef LDB
  #undef STG

  // ---- epilogue: 2-pass LDS transpose ([32][66] f32 per wave) + wide nt stores ----
  __syncthreads();
  float* tp = (float*)(gsm + w * 8448);
  const int ccl = (l & 3) * 16;
  const int cbase = bn * 128 + wn + ccl;
  f32x4 bs[4];
  #pragma unroll
  for (int jj = 0; jj < 4; ++jj) bs[jj] = *(const f32x4*)(ep.bias + cbase + jj * 4);

  #pragma unroll
  for (int q = 0; q < 2; ++q) {
    if (q == 1) { asm volatile("s_waitcnt lgkmcnt(0)" ::: "memory"); __builtin_amdgcn_sched_barrier(0); }
    #pragma unroll
    for (int mf2 = 0; mf2 < 2; ++mf2)
      #pragma unroll
      for (int nf = 0; nf < 4; ++nf)
        #pragma unroll
        for (int e = 0; e < 4; ++e)
          tp[(mf2 * 16 + lg * 4 + e) * 66 + nf * 16 + lr] = acc[q * 2 + mf2][nf][e];
    asm volatile("s_waitcnt lgkmcnt(0)" ::: "memory");
    __builtin_amdgcn_sched_barrier(0);

    #pragma unroll
    for (int pp = 0; pp < 2; ++pp) {
      const int rowl = pp * 16 + (l >> 2);
      const int r = bm * 128 + wm + q * 32 + rowl;
      const int c = cbase;
      f32x4 vv[4];
      #pragma unroll
      for (int jj = 0; jj < 4; ++jj) {
        #pragma unroll
        for (int j2 = 0; j2 < 4; ++j2)
          vv[jj][j2] = tp[rowl * 66 + ccl + jj * 4 + j2];
        vv[jj] += bs[jj];
      }

      if constexpr (EPI == 0) { // qkv: q/k wide nt; v scalar nt scatter (transposed layout)
        const int which = c / DIM;
        const int hdc = c - which * DIM;
        const int head = hdc >> 6, d0 = hdc & 63;
        const int win = r / NW, pos = r - win * NW;
        const size_t wh = (size_t)win * HEADS + head;
        if (which == 0) {
          uint32x4 o0, o1;
          o0[0] = pack2(vv[0][0] * QSCALE, vv[0][1] * QSCALE);
          o0[1] = pack2(vv[0][2] * QSCALE, vv[0][3] * QSCALE);
          o0[2] = pack2(vv[1][0] * QSCALE, vv[1][1] * QSCALE);
          o0[3] = pack2(vv[1][2] * QSCALE, vv[1][3] * QSCALE);
          o1[0] = pack2(vv[2][0] * QSCALE, vv[2][1] * QSCALE);
          o1[1] = pack2(vv[2][2] * QSCALE, vv[2][3] * QSCALE);
          o1[2] = pack2(vv[3][0] * QSCALE, vv[3][1] * QSCALE);
          o1[3] = pack2(vv[3][2] * QSCALE, vv[3][3] * QSCALE);
          u16* dst = ep.q + (wh * NW + pos) * HD + d0;
          __builtin_nontemporal_store(o0, (uint32x4*)dst);
          __builtin_nontemporal_store(o1, (uint32x4*)(dst + 8));
        } else if (which == 1) {
          uint32x4 o0, o1;
          o0[0] = pack2(vv[0][0], vv[0][1]); o0[1] = pack2(vv[0][2], vv[0][3]);
          o0[2] = pack2(vv[1][0], vv[1][1]); o0[3] = pack2(vv[1][2], vv[1][3]);
          o1[0] = pack2(vv[2][0], vv[2][1]); o1[1] = pack2(vv[2][2], vv[2][3]);
          o1[2] = pack2(vv[3][0], vv[3][1]); o1[3] = pack2(vv[3][2], vv[3][3]);
          u16* dst = ep.k + (wh * NW + pos) * HD + d0;
          __builtin_nontemporal_store(o0, (uint32x4*)dst);
          __builtin_nontemporal_store(o1, (uint32x4*)(dst + 8));
        } else {
          // scalar scatter: for fixed d, 16 lanes write consecutive pos -> HW-coalesced
          #pragma unroll
          for (int jj = 0; jj < 4; ++jj)
            #pragma unroll
            for (int j2 = 0; j2 < 4; ++j2)
              __builtin_nontemporal_store(f2b(vv[jj][j2]),
                  ep.v + (wh * HD + d0 + jj * 4 + j2) * NW + pos);
        }
      } else if constexpr (EPI == 1) { // proj: window-reverse + residual -> f32 d_out
        const int win = r / NW, pos = r - win * NW;
        const int b = win >> 4, wi = win & 15;
        const int hh = (wi >> 2) * 14 + pos / 14;
        const int ww2 = (wi & 3) * 14 + pos % 14;
        const size_t orow = (size_t)b * SEQL + hh * 56 + ww2;
        const f32x4* px = (const f32x4*)(ep.x + orow * DIM + c);
        f32x4* po = (f32x4*)(ep.outf + orow * DIM + c);
        #pragma unroll
        for (int jj = 0; jj < 4; ++jj) {
          f32x4 t2 = px[jj] + vv[jj];
          __builtin_nontemporal_store(t2, po + jj);
        }
      } else if constexpr (EPI == 2) { // fc1: cheap GELU -> bf16 wide nt
        float gg[16];
        #pragma unroll
        for (int jj = 0; jj < 4; ++jj)
          #pragma unroll
          for (int j2 = 0; j2 < 4; ++j2)
            gg[jj * 4 + j2] = gelu_f(vv[jj][j2]);
        uint32x4 o0, o1;
        o0[0] = pack2(gg[0], gg[1]);   o0[1] = pack2(gg[2], gg[3]);
        o0[2] = pack2(gg[4], gg[5]);   o0[3] = pack2(gg[6], gg[7]);
        o1[0] = pack2(gg[8], gg[9]);   o1[1] = pack2(gg[10], gg[11]);
        o1[2] = pack2(gg[12], gg[13]); o1[3] = pack2(gg[14], gg[15]);
        u16* dst = ep.o16 + (size_t)r * N + c;
        __builtin_nontemporal_store(o0, (uint32x4*)dst);
        __builtin_nontemporal_store(o1, (uint32x4*)(dst + 8));
      } else { // fc2: residual with d_out (x1): cached read, nt write
        f32x4* po = (f32x4*)(ep.outf + (size_t)r * N + c);
        #pragma unroll
        for (int jj = 0; jj < 4; ++jj) {
          f32x4 t2 = po[jj] + vv[jj];
          __builtin_nontemporal_store(t2, po + jj);
        }
      }
    }
  }
}

// ---------------- fused window attention (R17 best: sK staged + stride-65 T-table) ------
__global__ __launch_bounds__(256, 2)
void attn_kernel(const u16* __restrict__ qbuf, const u16* __restrict__ kbuf,
                 const u16* __restrict__ vt, const u16* __restrict__ rpb,
                 u16* __restrict__ abuf) {
  extern __shared__ __align__(16) char smem[];
  u16* sK = (u16*)smem;                  // [208][64], 16B-slot s -> s^(row&7)
  u16* sP = (u16*)(smem + 26624);        // 4 x [16][232]
  float* sT = (float*)(smem + 56320);    // 4 x [16][65] (stride 65 -> row r at bank r)

  const int tid = threadIdx.x;
  const int l = tid & 63, w = tid >> 6;
  const int lr = l & 15, lg = l >> 4;
  const int wh = blockIdx.x;             // win*12 + head
  const int win = wh / HEADS, head = wh - win * HEADS;

  const u16* Qg = qbuf + (size_t)wh * (NW * HD);
  const u16* Kg = kbuf + (size_t)wh * (NW * HD);
  const u16* Vg = vt + (size_t)wh * (HD * NW);   // [64][196]

  for (int t = tid; t < 1664; t += 256) {
    int r8 = t >> 3, c8 = t & 7;
    int s = (t & ~7) | (c8 ^ (r8 & 7));
    if (s >= 1568) s &= 1023;
    gl_lds16(Kg + s * 8, (char*)sK + t * 16);
  }
  __syncthreads();

  f32x4 zero4 = {0.f, 0.f, 0.f, 0.f};
  u16* myP = sP + w * (16 * 232);
  float* myT = sT + w * (16 * 65);

  for (int c = 0; c < 4; ++c) {
    const int chunk = w + 4 * c;
    if (chunk > 12) break;

    int qrow = chunk * 16 + lr; if (qrow > 195) qrow = 195;
    bf16x8 aq0 = *(const bf16x8*)(Qg + (size_t)qrow * HD + lg * 8);
    bf16x8 aq1 = *(const bf16x8*)(Qg + (size_t)qrow * HD + 32 + lg * 8);

    f32x4 th[2], tw[2];
    #pragma unroll
    for (int nf2 = 0; nf2 < 2; ++nf2) {
      const u16* bh = rpb + (nf2 * 16 + lr) * 64;
      const u16* bw = rpb + 2048 + (nf2 * 16 + lr) * 64;
      f32x4 a = zero4, b = zero4;
      a = MFMA_BF16(aq0, *(const bf16x8*)(bh + lg * 8), a, 0, 0, 0);
      a = MFMA_BF16(aq1, *(const bf16x8*)(bh + 32 + lg * 8), a, 0, 0, 0);
      b = MFMA_BF16(aq0, *(const bf16x8*)(bw + lg * 8), b, 0, 0, 0);
      b = MFMA_BF16(aq1, *(const bf16x8*)(bw + 32 + lg * 8), b, 0, 0, 0);
      th[nf2] = a; tw[nf2] = b;
    }
    #pragma unroll
    for (int nf2 = 0; nf2 < 2; ++nf2)
      #pragma unroll
      for (int e = 0; e < 4; ++e) {
        myT[(lg * 4 + e) * 65 + nf2 * 16 + lr]      = th[nf2][e];
        myT[(lg * 4 + e) * 65 + 32 + nf2 * 16 + lr] = tw[nf2][e];
      }

    f32x4 accs[13];
    #pragma unroll
    for (int nf = 0; nf < 13; ++nf) {
      int krow = nf * 16 + lr;
      int ksw = (krow & 7) << 3;
      bf16x8 b0 = *(const bf16x8*)(sK + krow * 64 + ((lg * 8) ^ ksw));
      bf16x8 b1 = *(const bf16x8*)(sK + krow * 64 + ((32 + lg * 8) ^ ksw));
      f32x4 cc = zero4;
      cc = MFMA_BF16(aq0, b0, cc, 0, 0, 0);
      cc = MFMA_BF16(aq1, b1, cc, 0, 0, 0);
      accs[nf] = cc;
    }

    int ihv[4], iwv[4];
    #pragma unroll
    for (int e = 0; e < 4; ++e) {
      int gi = chunk * 16 + lg * 4 + e;
      ihv[e] = (gi * 9363) >> 17;
      iwv[e] = gi - ihv[e] * 14;
    }
    float mrow[4] = {-3e38f, -3e38f, -3e38f, -3e38f};
    #pragma unroll
    for (int nf = 0; nf < 13; ++nf) {
      int j = nf * 16 + lr;
      int jh = (j * 9363) >> 17;
      int jw = j - jh * 14;
      #pragma unroll
      for (int e = 0; e < 4; ++e) {
        int ic = lg * 4 + e;
        float s = accs[nf][e]
                + myT[ic * 65 + ((ihv[e] - jh + 13) & 63)]
                + myT[ic * 65 + 32 + (iwv[e] - jw + 13)];
        if (nf == 12 && lr >= 4) s = -1e30f;
        accs[nf][e] = s;
        mrow[e] = fmaxf(mrow[e], s);
      }
    }
    #pragma unroll
    for (int e = 0; e < 4; ++e) {
      float v = mrow[e];
      v = fmaxf(v, __shfl_xor(v, 1)); v = fmaxf(v, __shfl_xor(v, 2));
      v = fmaxf(v, __shfl_xor(v, 4)); v = fmaxf(v, __shfl_xor(v, 8));
      mrow[e] = v;
    }
    float ssum[4] = {0.f, 0.f, 0.f, 0.f};
    #pragma unroll
    for (int nf = 0; nf < 13; ++nf)
      #pragma unroll
      for (int e = 0; e < 4; ++e) {
        float p = __expf(accs[nf][e] - mrow[e]);
        accs[nf][e] = p;
        ssum[e] += p;
      }
    #pragma unroll
    for (int e = 0; e < 4; ++e) {
      float v = ssum[e];
      v += __shfl_xor(v, 1); v += __shfl_xor(v, 2);
      v += __shfl_xor(v, 4); v += __shfl_xor(v, 8);
      ssum[e] = 1.f / v;
    }
    #pragma unroll
    for (int nf = 0; nf < 13; ++nf)
      #pragma unroll
      for (int e = 0; e < 4; ++e)
        myP[(lg * 4 + e) * 232 + nf * 16 + lr] = f2b(accs[nf][e] * ssum[e]);
    #pragma unroll
    for (int e = 0; e < 4; ++e)
      myP[(lg * 4 + e) * 232 + 208 + lr] = 0;

    f32x4 acco[4];
    #pragma unroll
    for (int nf = 0; nf < 4; ++nf) acco[nf] = zero4;
    #pragma unroll
    for (int ks = 0; ks < 7; ++ks) {
      bf16x8 ap = *(const bf16x8*)(myP + lr * 232 + ks * 32 + lg * 8);
      #pragma unroll
      for (int nf = 0; nf < 4; ++nf) {
        bf16x8 bv = ldg_b8(Vg + (size_t)(nf * 16 + lr) * NW + ks * 32 + lg * 8);
        acco[nf] = MFMA_BF16(ap, bv, acco[nf], 0, 0, 0);
      }
    }
    u16* ob = abuf + (size_t)win * NW * DIM + head * HD;
    #pragma unroll
    for (int nf = 0; nf < 4; ++nf)
      #pragma unroll
      for (int e = 0; e < 4; ++e) {
        int row = chunk * 16 + lg * 4 + e;
        if (row < 196) ob[(size_t)row * DIM + nf * 16 + lr] = f2b(acco[nf][e]);
      }
  }
}

// ---------------- host launch ---------------
extern "C" void kernel_launch(void* const* d_in, const int* in_sizes, int n_in,
                              void* d_out, int out_size, void* d_ws, size_t ws_size,
                              hipStream_t stream) {
  (void)in_sizes; (void)n_in; (void)out_size; (void)ws_size;
  const float* x    = (const float*)d_in[0];
  const float* ln1s = (const float*)d_in[1];
  const float* ln1b = (const float*)d_in[2];
  const float* qkvw = (const float*)d_in[3];
  const float* qkvb = (const float*)d_in[4];
  const float* rph  = (const float*)d_in[5];
  const float* rpw  = (const float*)d_in[6];
  const float* pjw  = (const float*)d_in[7];
  const float* pjb  = (const float*)d_in[8];
  const float* ln2s = (const float*)d_in[9];
  const float* ln2b = (const float*)d_in[10];
  const float* f1w  = (const float*)d_in[11];
  const float* f1b  = (const float*)d_in[12];
  const float* f2w  = (const float*)d_in[13];
  const float* f2b_ = (const float*)d_in[14];
  float* out = (float*)d_out;

  char* ws = (char*)d_ws;
  u16* qkvwT = (u16*)ws;              // packed [2304x768]
  u16* projwT = qkvwT + 1769472;      // packed [768x768]
  u16* fc1wT  = qkvwT + 2359296;      // packed [3072x768]
  u16* fc2wT  = qkvwT + 4718592;      // packed [768x3072]
  u16* xw   = (u16*)(ws + 14155776);  // [25088][768]
  u16* qbuf = (u16*)(ws + 52690944);  // [1536][196][64]
  u16* kbuf = qbuf + 19267584;
  u16* vtb  = kbuf + 19267584;        // [1536][64][196]
  u16* h2   = (u16*)(ws + 168296448); // [25088][768]
  u16* abuf = xw;                     // alias (xw dead after qkv gemm)
  u16* h1   = xw;                     // [25088][3072] spans xw+q+k+vT regions (all dead)
  u16* rpb  = h2;                     // [2][32][64] bf16 tables; h2 written only after attn

  (void)hipFuncSetAttribute((const void*)attn_kernel,
                            hipFuncAttributeMaxDynamicSharedMemorySize, ATTN_SMEM);
  (void)hipFuncSetAttribute((const void*)gemm6_ep<768, 2304, 0>,
                            hipFuncAttributeMaxDynamicSharedMemorySize, GEMM_SMEM);
  (void)hipFuncSetAttribute((const void*)gemm6_ep<768, 768, 1>,
                            hipFuncAttributeMaxDynamicSharedMemorySize, GEMM_SMEM);
  (void)hipFuncSetAttribute((const void*)gemm6_ep<768, 3072, 2>,
                            hipFuncAttributeMaxDynamicSharedMemorySize, GEMM_SMEM);
  (void)hipFuncSetAttribute((const void*)gemm6_ep<3072, 768, 3>,
                            hipFuncAttributeMaxDynamicSharedMemorySize, GEMM_SMEM);

  prep_all<<<3472, 256, 0, stream>>>(qkvw, pjw, f1w, f2w, rph, rpw,
                                     qkvwT, projwT, fc1wT, fc2wT, rpb);

  ln_kernel<true><<<MROWS / 4, 256, 0, stream>>>(x, ln1s, ln1b, xw);

  { Epi e{}; e.bias = qkvb; e.q = qbuf; e.k = kbuf; e.v = vtb;
    gemm6_ep<768, 2304, 0><<<196 * 18, 256, GEMM_SMEM, stream>>>(xw, qkvwT, e); }

  attn_kernel<<<1536, 256, ATTN_SMEM, stream>>>(qbuf, kbuf, vtb, rpb, abuf);

  { Epi e{}; e.bias = pjb; e.x = x; e.outf = out;
    gemm6_ep<768, 768, 1><<<196 * 6, 256, GEMM_SMEM, stream>>>(abuf, projwT, e); }

  ln_kernel<false><<<MROWS / 4, 256, 0, stream>>>(out, ln2s, ln2b, h2);

  { Epi e{}; e.bias = f1b; e.o16 = h1;
    gemm6_ep<768, 3072, 2><<<196 * 24, 256, GEMM_SMEM, stream>>>(h2, fc1wT, e); }

  { Epi e{}; e.bias = f2b_; e.outf = out;
    gemm6_ep<3072, 768, 3><<<196 * 6, 256, GEMM_SMEM, stream>>>(h1, fc2wT, e); }
}